// Round 18
// baseline (32.273 us; speedup 1.0000x reference)
//
#include <hip/hip_runtime.h>
#include <math.h>

#define TOKENS 16384
#define DIM 2048
#define NE 8
#define BLOCK 1024             // 16 waves, 1 block/CU (128 KiB LDS)
#define GRID 256
#define NCHUNK 8               // 8 chunks of 64 float4

// DPP cross-lane (VALU pipe, not DS)
template <int CTRL>
__device__ __forceinline__ float dpp_mov(float v) {
    return __int_as_float(__builtin_amdgcn_update_dpp(
        0, __float_as_int(v), CTRL, 0xf, 0xf, true));
}
#define DPP_XOR1 0xB1   // quad_perm [1,0,3,2]
#define DPP_XOR2 0x4E   // quad_perm [2,3,0,1]
#define DPP_XOR8 0x128  // row_ror:8 == xor-8 within each 16-lane row

// async global->LDS, 16B/lane: LDS dest = wave-uniform base + lane*16
__device__ __forceinline__ void stage16(const float* g, float* l) {
    __builtin_amdgcn_global_load_lds(
        (const __attribute__((address_space(1))) void*)g,
        (__attribute__((address_space(3))) void*)l, 16, 0, 0);
}

#define FMA_BODY(XBUF, KC)                                         \
    {                                                              \
        const int kk = (KC);                                       \
        _Pragma("unroll")                                          \
        for (int r = 0; r < 16; ++r) {                             \
            const float4 w = wl4[r * (DIM / 4) + kk * 64 + lane];  \
            _Pragma("unroll")                                      \
            for (int t = 0; t < 4; ++t) {                          \
                float a = V[r * 4 + t];                            \
                a = fmaf(XBUF[t].x, w.x, a);                       \
                a = fmaf(XBUF[t].y, w.y, a);                       \
                a = fmaf(XBUF[t].z, w.z, a);                       \
                a = fmaf(XBUF[t].w, w.w, a);                       \
                V[r * 4 + t] = a;                                  \
            }                                                      \
        }                                                          \
    }
#define REFILL(XBUF, KC)                                           \
    {                                                              \
        const int kk = (KC);                                       \
        _Pragma("unroll")                                          \
        for (int t = 0; t < 4; ++t)                                \
            XBUF[t] = x4[(t0 + t) * (DIM / 4) + kk * 64 + lane];   \
    }

__launch_bounds__(BLOCK, 4)   // full-unroll shape: allocator picks >=128 VGPR
__global__ void router_kernel(const float* __restrict__ x,
                              const float* __restrict__ w_g,
                              const float* __restrict__ w_noise,
                              const float* __restrict__ eps,
                              float* __restrict__ out)
{
    __shared__ float wlds[16 * DIM];   // rows 0..7 = w_g, 8..15 = w_noise

    const int tid  = threadIdx.x;
    const int lane = tid & 63;
    const int wv   = tid >> 6;                   // 0..15
    const int t0   = (blockIdx.x * 16 + wv) * 4; // this wave's 4 tokens
    const int off  = wv & 3;                     // convoy phase within each half

    // chunk schedule: {0..3} rotated by off, then {4..7} rotated by off
    int c[8];
    #pragma unroll
    for (int j = 0; j < 8; ++j)
        c[j] = ((j + off) & 3) + ((j >= 4) ? 4 : 0);

    // wave w stages weight row w (rows 0..7 = w_g, 8..15 = w_noise)
    const float* wrow = (wv < 8) ? (w_g + wv * DIM) : (w_noise + (wv - 8) * DIM);
    float* lrow = &wlds[wv * DIM];

    // ---- issue half-0 weight staging: async, direct-to-LDS, zero VGPRs ----
    #pragma unroll
    for (int i = 0; i < 4; ++i)
        stage16(wrow + i * 256 + lane * 4, lrow + i * 256);

    // ---- x prefetch for first two scheduled chunks (overlaps staging) ----
    const float4* x4 = (const float4*)x;
    float4 xvA[4], xvB[4];
    #pragma unroll
    for (int t = 0; t < 4; ++t) xvA[t] = x4[(t0 + t) * (DIM / 4) + c[0] * 64 + lane];
    #pragma unroll
    for (int t = 0; t < 4; ++t) xvB[t] = x4[(t0 + t) * (DIM / 4) + c[1] * 64 + lane];

    float my_eps = 0.f;
    if (lane < 32) my_eps = eps[t0 * NE + lane];

    __syncthreads();                   // half-0 weights resident

    // ---- issue half-1 staging now; its latency hides under half-0 compute ----
    #pragma unroll
    for (int i = 0; i < 4; ++i)
        stage16(wrow + 1024 + i * 256 + lane * 4, lrow + 1024 + i * 256);

    const float4* wl4 = (const float4*)wlds;

    float V[64];                       // V[r*4+t]
    #pragma unroll
    for (int v = 0; v < 64; ++v) V[v] = 0.f;

    FMA_BODY(xvA, c[0]); REFILL(xvA, c[2]);
    FMA_BODY(xvB, c[1]); REFILL(xvB, c[3]);
    FMA_BODY(xvA, c[2]); REFILL(xvA, c[4]);
    FMA_BODY(xvB, c[3]); REFILL(xvB, c[5]);

    __syncthreads();                   // half-1 weights resident

    FMA_BODY(xvA, c[4]); REFILL(xvA, c[6]);
    FMA_BODY(xvB, c[5]); REFILL(xvB, c[7]);
    FMA_BODY(xvA, c[6]);
    FMA_BODY(xvB, c[7]);

    // ---- pack-halving reduction: DPP stages 0,1,3; shfl stages 2,4,5 ----
    #pragma unroll
    for (int j = 0; j < 32; ++j) {     // s=0: xor-1 (DPP)
        const float A = V[2 * j], B = V[2 * j + 1];
        const float As = dpp_mov<DPP_XOR1>(A);
        const float Bs = dpp_mov<DPP_XOR1>(B);
        V[j] = (lane & 1) ? (B + Bs) : (A + As);
    }
    #pragma unroll
    for (int j = 0; j < 16; ++j) {     // s=1: xor-2 (DPP)
        const float A = V[2 * j], B = V[2 * j + 1];
        const float As = dpp_mov<DPP_XOR2>(A);
        const float Bs = dpp_mov<DPP_XOR2>(B);
        V[j] = (lane & 2) ? (B + Bs) : (A + As);
    }
    #pragma unroll
    for (int j = 0; j < 8; ++j) {      // s=2: xor-4 (shfl)
        const float A = V[2 * j], B = V[2 * j + 1];
        const float As = __shfl_xor(A, 4, 64);
        const float Bs = __shfl_xor(B, 4, 64);
        V[j] = (lane & 4) ? (B + Bs) : (A + As);
    }
    #pragma unroll
    for (int j = 0; j < 4; ++j) {      // s=3: xor-8 (DPP row_ror:8)
        const float A = V[2 * j], B = V[2 * j + 1];
        const float As = dpp_mov<DPP_XOR8>(A);
        const float Bs = dpp_mov<DPP_XOR8>(B);
        V[j] = (lane & 8) ? (B + Bs) : (A + As);
    }
    #pragma unroll
    for (int j = 0; j < 2; ++j) {      // s=4: xor-16 (shfl)
        const float A = V[2 * j], B = V[2 * j + 1];
        const float As = __shfl_xor(A, 16, 64);
        const float Bs = __shfl_xor(B, 16, 64);
        V[j] = (lane & 16) ? (B + Bs) : (A + As);
    }
    {                                  // s=5: xor-32 (shfl)
        const float A = V[0], B = V[1];
        const float As = __shfl_xor(A, 32, 64);
        const float Bs = __shfl_xor(B, 32, 64);
        V[0] = (lane & 32) ? (B + Bs) : (A + As);
    }
    const float mine = V[0];           // lane L: row (L>>2), token t0+(L&3)

    const float other = __shfl_xor(mine, 32, 64);

    if (lane < 32) {
        const int e = lane >> 2;
        const int t = lane & 3;
        const int tok = t0 + t;

        const float ev = __shfl(my_eps, (t << 3) | e, 64);

        const float nv = other;
        const float sp = fmaxf(nv, 0.f) + log1pf(expf(-fabsf(nv)));  // stable softplus
        const float logit = fmaf(sp, ev, mine);

        // top-2 across the 8 lanes sharing token t (e lives in lane bits 2..4)
        float v1 = logit, v2 = -INFINITY;
        int   i1 = e,     i2 = 7;
        #pragma unroll
        for (int sm = 2; sm <= 4; ++sm) {
            const int m = 1 << sm;
            const float ov1 = __shfl_xor(v1, m, 64);
            const float ov2 = __shfl_xor(v2, m, 64);
            const int   oi1 = __shfl_xor(i1, m, 64);
            const int   oi2 = __shfl_xor(i2, m, 64);
            const bool firstA = (v1 > ov1) || (v1 == ov1 && i1 < oi1);
            const float nv1 = firstA ? v1  : ov1;
            const int   ni1 = firstA ? i1  : oi1;
            const float ca  = firstA ? ov1 : v1;
            const int   cia = firstA ? oi1 : i1;
            const float cb  = firstA ? v2  : ov2;
            const int   cib = firstA ? i2  : oi2;
            const bool secondA = (ca > cb) || (ca == cb && cia < cib);
            v1 = nv1; i1 = ni1;
            v2 = secondA ? ca : cb;
            i2 = secondA ? cia : cib;
        }

        if (e == 0) {                  // lanes 0..3: lane == t
            *(float2*)&out[2 * tok] = make_float2(v1, v2);
            *(float2*)&out[2 * TOKENS + 2 * tok] = make_float2((float)i1, (float)i2);
        }
    }
}

extern "C" void kernel_launch(void* const* d_in, const int* in_sizes, int n_in,
                              void* d_out, int out_size, void* d_ws, size_t ws_size,
                              hipStream_t stream) {
    const float* x       = (const float*)d_in[0];
    const float* w_g     = (const float*)d_in[1];
    const float* w_noise = (const float*)d_in[2];
    const float* eps     = (const float*)d_in[3];
    float* out = (float*)d_out;

    router_kernel<<<GRID, BLOCK, 0, stream>>>(x, w_g, w_noise, eps, out);
}